// Round 14
// baseline (284.511 us; speedup 1.0000x reference)
//
#include <hip/hip_runtime.h>
#include <hip/hip_fp16.h>
#include <cmath>

typedef _Float16 f16;
typedef _Float16 f16x8 __attribute__((ext_vector_type(8)));
typedef float f32x4 __attribute__((ext_vector_type(4)));

#define B_ 128
#define N_ 512
#define H_ 64
#define K_ 16

__device__ __forceinline__ float elu_(float x) { return x > 0.f ? x : (__expf(x) - 1.f); }
__device__ __forceinline__ unsigned umin_(unsigned a, unsigned b) { return a < b ? a : b; }
__device__ __forceinline__ unsigned umax_(unsigned a, unsigned b) { return a > b ? a : b; }
__device__ __forceinline__ f32x4 mfma16(f16x8 a, f16x8 b, f32x4 c) {
    return __builtin_amdgcn_mfma_f32_16x16x32_f16(a, b, c, 0, 0, 0);
}
__device__ __forceinline__ f32x4 splat4(float v) { f32x4 r; r[0]=v; r[1]=v; r[2]=v; r[3]=v; return r; }
__device__ __forceinline__ unsigned mbcnt_(unsigned long long mask) {
    return __builtin_amdgcn_mbcnt_hi((unsigned)(mask >> 32),
           __builtin_amdgcn_mbcnt_lo((unsigned)mask, 0u));
}
__device__ __forceinline__ f16 hexp_(f16 x) {
    __half h = *(__half*)&x; h = hexp(h); return *(f16*)&h;
}
// packed-f16 elu on 8 lanes: elu(x) = max(x,0) + exp(min(x,0)) - 1
__device__ __forceinline__ f16x8 elu8h_(f16x8 x) {
    f16x8 z; f16x8 one;
    #pragma unroll
    for (int i = 0; i < 8; ++i) { z[i] = (f16)0.f; one[i] = (f16)1.f; }
    f16x8 mx = __builtin_elementwise_max(x, z);
    f16x8 mn = __builtin_elementwise_min(x, z);
    f16x8 e;
    #pragma unroll
    for (int i = 0; i < 8; ++i) e[i] = hexp_(mn[i]);
    return mx + e - one;
}
// wave-wide max via DPP (VALU pipe, no ds_swizzle); canonical shr/bcast chain.
__device__ __forceinline__ unsigned wmax64_(unsigned v) {
    v = umax_(v, (unsigned)__builtin_amdgcn_update_dpp(0, (int)v, 0x111, 0xf, 0xf, true)); // row_shr:1
    v = umax_(v, (unsigned)__builtin_amdgcn_update_dpp(0, (int)v, 0x112, 0xf, 0xf, true)); // row_shr:2
    v = umax_(v, (unsigned)__builtin_amdgcn_update_dpp(0, (int)v, 0x114, 0xf, 0xf, true)); // row_shr:4
    v = umax_(v, (unsigned)__builtin_amdgcn_update_dpp(0, (int)v, 0x118, 0xf, 0xf, true)); // row_shr:8
    v = umax_(v, (unsigned)__builtin_amdgcn_update_dpp(0, (int)v, 0x142, 0xa, 0xf, true)); // row_bcast:15
    v = umax_(v, (unsigned)__builtin_amdgcn_update_dpp(0, (int)v, 0x143, 0xc, 0xf, true)); // row_bcast:31
    return (unsigned)__builtin_amdgcn_readlane((int)v, 63);
}
// add-reduce within each 16-lane row toward lane0 (valid in lane0 of each row)
__device__ __forceinline__ float rsum16lo_(float x) {
    x += __int_as_float(__builtin_amdgcn_update_dpp(0, __float_as_int(x), 0x101, 0xf, 0xf, true));
    x += __int_as_float(__builtin_amdgcn_update_dpp(0, __float_as_int(x), 0x102, 0xf, 0xf, true));
    x += __int_as_float(__builtin_amdgcn_update_dpp(0, __float_as_int(x), 0x104, 0xf, 0xf, true));
    x += __int_as_float(__builtin_amdgcn_update_dpp(0, __float_as_int(x), 0x108, 0xf, 0xf, true));
    return x;
}

// ---------------------------------------------------------------------------
// Fused input MLP (3 layers) + sq-norms. The per-wave LDS tile is PRIVATE
// (indexed by wid), so NO barriers are needed: same-wave LDS RAW is ordered
// by lgkmcnt. Waves run their 5-GEMM chains fully independently.
// grid 1024 x block 256.
// ---------------------------------------------------------------------------
__global__ __launch_bounds__(256) void mlp_kernel(const float* __restrict__ x,
        const float* __restrict__ W0, const float* __restrict__ b0,
        const float* __restrict__ W1, const float* __restrict__ b1,
        const float* __restrict__ W2, const float* __restrict__ b2,
        f16* __restrict__ hout, float* __restrict__ sqout)
{
    __shared__ f16 tile[4][16*72];
    const int lane = threadIdx.x & 63, wid = threadIdx.x >> 6;
    const int m = lane & 15, q = lane >> 4;
    const int rowbase = blockIdx.x*64 + wid*16;
    f16* tw = tile[wid];

    // ---- layer 0: A = x (K=5 padded to 32) ----
    f16x8 af0, af1;
    {
        const float* xp = x + (size_t)(rowbase + m)*5;
        #pragma unroll
        for (int jj = 0; jj < 8; ++jj) { int k = q*8+jj; af0[jj] = (k < 5) ? (f16)xp[k] : (f16)0.f; }
    }
    f32x4 acc[4];
    #pragma unroll
    for (int t = 0; t < 4; ++t) {
        f16x8 bf;
        #pragma unroll
        for (int jj = 0; jj < 8; ++jj) { int k = q*8+jj; bf[jj] = (k < 5) ? (f16)W0[k*64 + t*16+m] : (f16)0.f; }
        acc[t] = splat4(b0[t*16+m]);
        acc[t] = mfma16(af0, bf, acc[t]);
    }
    #pragma unroll
    for (int t = 0; t < 4; ++t)
        #pragma unroll
        for (int r = 0; r < 4; ++r)
            tw[(q*4+r)*72 + t*16+m] = (f16)elu_(acc[t][r]);
    af0 = *(const f16x8*)(tw + m*72 + q*8);
    af1 = *(const f16x8*)(tw + m*72 + q*8 + 32);

    // ---- layer 1 ----
    #pragma unroll
    for (int t = 0; t < 4; ++t) {
        f16x8 bfa, bfb;
        #pragma unroll
        for (int jj = 0; jj < 8; ++jj) {
            bfa[jj] = (f16)W1[(q*8+jj)*64 + t*16+m];
            bfb[jj] = (f16)W1[(q*8+jj+32)*64 + t*16+m];
        }
        acc[t] = splat4(b1[t*16+m]);
        acc[t] = mfma16(af0, bfa, acc[t]);
        acc[t] = mfma16(af1, bfb, acc[t]);
    }
    #pragma unroll
    for (int t = 0; t < 4; ++t)
        #pragma unroll
        for (int r = 0; r < 4; ++r)
            tw[(q*4+r)*72 + t*16+m] = (f16)elu_(acc[t][r]);
    af0 = *(const f16x8*)(tw + m*72 + q*8);
    af1 = *(const f16x8*)(tw + m*72 + q*8 + 32);

    // ---- layer 2 (+ h store + sq) ----
    #pragma unroll
    for (int t = 0; t < 4; ++t) {
        f16x8 bfa, bfb;
        #pragma unroll
        for (int jj = 0; jj < 8; ++jj) {
            bfa[jj] = (f16)W2[(q*8+jj)*64 + t*16+m];
            bfb[jj] = (f16)W2[(q*8+jj+32)*64 + t*16+m];
        }
        acc[t] = splat4(b2[t*16+m]);
        acc[t] = mfma16(af0, bfa, acc[t]);
        acc[t] = mfma16(af1, bfb, acc[t]);
    }
    float s[4] = {0.f,0.f,0.f,0.f};
    #pragma unroll
    for (int t = 0; t < 4; ++t)
        #pragma unroll
        for (int r = 0; r < 4; ++r) {
            float v = elu_(acc[t][r]);
            hout[(size_t)(rowbase + q*4 + r)*64 + t*16 + m] = (f16)v;
            s[r] += v*v;
        }
    #pragma unroll
    for (int r = 0; r < 4; ++r) s[r] = rsum16lo_(s[r]);
    if (m == 0) {
        #pragma unroll
        for (int r = 0; r < 4; ++r) sqout[rowbase + q*4 + r] = s[r];
    }
}

// ---------------------------------------------------------------------------
// kNN (R9/R13 form, unchanged — 54.2 us measured): block 512, 4 blocks/CU at
// 32 KB LDS. Gram via MFMA; rank-17 ballot bit-descend threshold; batched-
// ballot compact; self-kill + DPP max-removal; fused next-layer P/Q
// projection after selection. grid 4096 x block 512.
// ---------------------------------------------------------------------------
__global__ __launch_bounds__(512, 8) void knn_kernel(const f16* __restrict__ hin,
        const float* __restrict__ sq, int* __restrict__ idxout,
        const float* __restrict__ We, const float* __restrict__ be,
        f16* __restrict__ Pout, f16* __restrict__ Qout)
{
    __shared__ unsigned keys[16*512];      // 32768 B exactly
    const int lane = threadIdx.x & 63;
    const int wid  = threadIdx.x >> 6;     // 0..7
    const int m = lane & 15, q = lane >> 4;
    const int b  = blockIdx.x >> 5;
    const int rt = blockIdx.x & 31;
    const int rowbase = rt*16;
    const f16* hb = hin + (size_t)b*N_*H_;
    const float* sqb = sq + b*N_;

    f16x8 af0, af1;
    {
        const f16* Ap = hb + (size_t)(rowbase + m)*64 + q*8;
        af0 = *(const f16x8*)Ap;
        af1 = *(const f16x8*)(Ap + 32);
    }
    const int colb0 = wid*16;
    f16x8 bf0[4], bf1[4];
    float sc[4];
    #pragma unroll
    for (int cti = 0; cti < 4; ++cti) {
        const f16* Bp = hb + (size_t)(colb0 + cti*128 + m)*64 + q*8;
        bf0[cti] = *(const f16x8*)Bp;
        bf1[cti] = *(const f16x8*)(Bp + 32);
        sc[cti] = sqb[colb0 + cti*128 + m];
    }
    int base_r[4];
    #pragma unroll
    for (int r = 0; r < 4; ++r) {
        const int row = q*4 + r;
        base_r[r] = row*512 + ((colb0 + m) ^ (row << 1));
    }
    #pragma unroll
    for (int cti = 0; cti < 4; ++cti) {
        f32x4 acc = splat4(0.f);
        acc = mfma16(af0, bf0[cti], acc);
        acc = mfma16(af1, bf1[cti], acc);
        #pragma unroll
        for (int r = 0; r < 4; ++r) {
            float d = fmaf(-2.f, acc[r], sc[cti]);   // sq_i dropped: row-constant
            unsigned u = __float_as_uint(d);
            u ^= (0x80000000u | (unsigned)((int)u >> 31));   // monotone order map
            unsigned key = (u & 0xFFFFFE00u) | (unsigned)(colb0 + cti*128 + m);
            keys[base_r[r] + cti*128] = key;         // immediate offset cti*512B
        }
    }
    __syncthreads();

    unsigned kk[2][8];
    #pragma unroll
    for (int rr = 0; rr < 2; ++rr) {
        const int ri = wid*2 + rr;
        *(uint4*)&kk[rr][0] = *(const uint4*)(keys + ri*512 + lane*4);
        *(uint4*)&kk[rr][4] = *(const uint4*)(keys + ri*512 + 256 + lane*4);
    }
    unsigned* scr = keys + wid*2*512;   // wave's own dead rows

    // ---- Phase A: per-lane min8, rank-17 ballot bit-descend threshold ----
    unsigned v[2];
    #pragma unroll
    for (int rr = 0; rr < 2; ++rr) {
        unsigned mn = kk[rr][0];
        #pragma unroll
        for (int s2 = 1; s2 < 8; ++s2) mn = umin_(mn, kk[rr][s2]);
        v[rr] = mn;
    }
    unsigned T[2] = {0u,0u};
    #pragma unroll
    for (int bit = 31; bit >= 9; --bit) {
        #pragma unroll
        for (int rr = 0; rr < 2; ++rr) {
            unsigned cand = T[rr] | (1u << bit);
            int c = __popcll(__ballot(v[rr] < cand));
            T[rr] = (c < 17) ? cand : T[rr];
        }
    }
    T[0] |= 511u; T[1] |= 511u;   // >=17 keys <= T (incl self)

    // ---- Phase B: batched-ballot compact ----
    unsigned cnt[2];
    #pragma unroll
    for (int rr = 0; rr < 2; ++rr) {
        unsigned long long bal[8];
        #pragma unroll
        for (int s2 = 0; s2 < 8; ++s2) bal[s2] = __ballot(kk[rr][s2] <= T[rr]);
        unsigned base = 0;
        #pragma unroll
        for (int s2 = 0; s2 < 8; ++s2) {
            if (kk[rr][s2] <= T[rr]) {
                unsigned pos = base + mbcnt_(bal[s2]);
                if (pos < 64u) scr[rr*64 + pos] = kk[rr][s2];
            }
            base += (unsigned)__popcll(bal[s2]);
        }
        cnt[rr] = base;
    }

    // ---- Phase C: kill self, DPP max-removal of (actives-16) largest ----
    #pragma unroll
    for (int rr = 0; rr < 2; ++rr) {
        const unsigned cc_ = umin_(cnt[rr], 64u);
        const int ri = wid*2 + rr;
        const unsigned rowglob = (unsigned)(rowbase + ri);
        bool act = lane < (int)cc_;
        unsigned mv = act ? scr[rr*64 + lane] : 0u;
        if (act && (mv & 511u) == rowglob) { act = false; mv = 0u; }  // self
        int e = __popcll(__ballot(act)) - 16;
        while (e > 0) {
            unsigned mx = wmax64_(mv);
            if (mv == mx) { act = false; mv = 0u; }
            --e;
        }
        int* outp = idxout + ((size_t)b*N_ + rowglob)*K_;
        unsigned long long bal = __ballot(act);       // exactly 16 lanes
        unsigned rank = mbcnt_(bal);
        if (act) outp[rank] = (int)(mv & 511u);
    }

    // ---- fused P/Q projection AFTER selection (hides in wave overlap) ----
    {
        const int t = wid & 3;
        f32x4 acc = (wid < 4) ? splat4(be[t*16+m]) : splat4(0.f);
        #pragma unroll
        for (int cc = 0; cc < 2; ++cc) {
            const f16x8 afc = cc ? af1 : af0;
            f16x8 bb;
            if (wid < 4) {
                #pragma unroll
                for (int jj = 0; jj < 8; ++jj) {
                    float wa = We[(q*8+jj+32*cc)*64 + t*16+m];
                    float wb = We[(q*8+jj+32*cc+64)*64 + t*16+m];
                    bb[jj] = (f16)(wa - wb);
                }
            } else {
                #pragma unroll
                for (int jj = 0; jj < 8; ++jj)
                    bb[jj] = (f16)We[(q*8+jj+32*cc+64)*64 + t*16+m];
            }
            acc = mfma16(afc, bb, acc);
        }
        f16* outp = (wid < 4) ? Pout : Qout;
        #pragma unroll
        for (int r = 0; r < 4; ++r)
            outp[((size_t)b*N_ + rowbase + q*4 + r)*64 + t*16 + m] = (f16)acc[r];
    }
}

// ---------------------------------------------------------------------------
// EdgeConv layer2 + sum aggregation + fused sq-norm (R13 form, unchanged).
// 2-node interleave hides gather latency; DPP reductions. grid 2048 x 256.
// ---------------------------------------------------------------------------
__device__ __forceinline__ void edge_node_(size_t r0, f16x8 pa, f16x8 pb,
        f16x8 qa, f16x8 qb, const f16x8 (&bf)[2][4], const float (&bcol)[4],
        f16* __restrict__ out, float* __restrict__ sqout, int lane)
{
    f16x8 af0 = elu8h_(pa + qa);
    f16x8 af1 = elu8h_(pb + qb);
    f32x4 acc[4];
    #pragma unroll
    for (int t = 0; t < 4; ++t) acc[t] = splat4(bcol[t]);
    #pragma unroll
    for (int t = 0; t < 4; ++t) acc[t] = mfma16(af0, bf[0][t], acc[t]);
    #pragma unroll
    for (int t = 0; t < 4; ++t) acc[t] = mfma16(af1, bf[1][t], acc[t]);
    float ssum = 0.f;
    #pragma unroll
    for (int t = 0; t < 4; ++t) {
        float s = elu_(acc[t][0]) + elu_(acc[t][1]) + elu_(acc[t][2]) + elu_(acc[t][3]);
        s += __shfl_xor(s, 16);
        s += __shfl_xor(s, 32);
        if (lane < 16) out[r0*64 + t*16 + lane] = (f16)s;
        ssum += s*s;
    }
    ssum = rsum16lo_(ssum);
    if (lane == 0) sqout[r0] = ssum;
}

__global__ __launch_bounds__(256, 5) void edge_kernel(const f16* __restrict__ P,
        const f16* __restrict__ Q, const int* __restrict__ idx,
        const float* __restrict__ W1, const float* __restrict__ b1,
        f16* __restrict__ out, float* __restrict__ sqout)
{
    const int lane = threadIdx.x & 63;
    const int wid  = threadIdx.x >> 6;
    const int m = lane & 15, q = lane >> 4;

    f16x8 bf[2][4];
    #pragma unroll
    for (int cc = 0; cc < 2; ++cc)
        #pragma unroll
        for (int t = 0; t < 4; ++t)
            #pragma unroll
            for (int jj = 0; jj < 8; ++jj)
                bf[cc][t][jj] = (f16)W1[(q*8 + jj + 32*cc)*64 + t*16 + m];
    float bcol[4];
    #pragma unroll
    for (int t = 0; t < 4; ++t) bcol[t] = b1[t*16 + m];

    const int node0 = blockIdx.x*32 + wid*8;
    const int gbase = node0 & ~(N_-1);
    const int c0a = q*8, c0b = q*8 + 32;
    int jv[8];
    #pragma unroll
    for (int i = 0; i < 8; ++i) jv[i] = idx[(size_t)(node0 + i)*K_ + m];

    #pragma unroll
    for (int ip = 0; ip < 4; ++ip) {
        const size_t r0 = (size_t)(node0 + 2*ip);
        const size_t r1 = r0 + 1;
        const size_t g0 = (size_t)(gbase + jv[2*ip]);
        const size_t g1 = (size_t)(gbase + jv[2*ip+1]);
        f16x8 p0a = *(const f16x8*)(P + r0*64 + c0a);
        f16x8 p0b = *(const f16x8*)(P + r0*64 + c0b);
        f16x8 q0a = *(const f16x8*)(Q + g0*64 + c0a);
        f16x8 q0b = *(const f16x8*)(Q + g0*64 + c0b);
        f16x8 p1a = *(const f16x8*)(P + r1*64 + c0a);
        f16x8 p1b = *(const f16x8*)(P + r1*64 + c0b);
        f16x8 q1a = *(const f16x8*)(Q + g1*64 + c0a);
        f16x8 q1b = *(const f16x8*)(Q + g1*64 + c0b);
        edge_node_(r0, p0a, p0b, q0a, q0b, bf, bcol, out, sqout, lane);
        edge_node_(r1, p1a, p1b, q1a, q1b, bf, bcol, out, sqout, lane);
    }
}

// ---------------------------------------------------------------------------
// Global max-pool + 3-layer output MLP + log_softmax. Block 512 (8 waves):
// twice the loads in flight for the 64 KB/block h read, 8-way split dots.
// grid 128 x block 512.
// ---------------------------------------------------------------------------
__global__ __launch_bounds__(512) void final_kernel(const f16* __restrict__ hin,
        const float* __restrict__ Wo0, const float* __restrict__ bo0,
        const float* __restrict__ Wo1, const float* __restrict__ bo1,
        const float* __restrict__ Wo2, const float* __restrict__ bo2,
        float* __restrict__ out)
{
    __shared__ float smax[64][64];
    __shared__ float g0[64], g1[64], g2[64], part[8][64], lg[10];
    const int t = threadIdx.x;
    const int b = blockIdx.x;
    const int cg = t & 7, rg = t >> 3;     // col-group 0..7 (8 cols), row-group 0..63

    float mx[8];
    #pragma unroll
    for (int e = 0; e < 8; ++e) mx[e] = -3.0e38f;
    #pragma unroll
    for (int i = 0; i < 8; ++i) {
        const int row = rg + i*64;
        f16x8 vv = *(const f16x8*)(hin + ((size_t)b*N_ + row)*64 + cg*8);
        #pragma unroll
        for (int e = 0; e < 8; ++e) mx[e] = fmaxf(mx[e], (float)vv[e]);
    }
    #pragma unroll
    for (int e = 0; e < 8; ++e) smax[rg][cg*8 + e] = mx[e];
    __syncthreads();
    for (int s = 32; s >= 1; s >>= 1) {
        if (rg < s) {
            #pragma unroll
            for (int e = 0; e < 8; ++e)
                smax[rg][cg*8+e] = fmaxf(smax[rg][cg*8+e], smax[rg+s][cg*8+e]);
        }
        __syncthreads();
    }
    if (t < 64) g0[t] = smax[0][t];
    __syncthreads();

    const int j = t & 63, p = t >> 6;      // p 0..7: 8-way split of the dot
    {
        float a = 0.f;
        #pragma unroll
        for (int c = 0; c < 8; ++c) a += g0[p*8 + c]*Wo0[(p*8 + c)*64 + j];
        part[p][j] = a;
    }
    __syncthreads();
    if (t < 64) {
        float a = bo0[t];
        #pragma unroll
        for (int p2 = 0; p2 < 8; ++p2) a += part[p2][t];
        g1[t] = elu_(a);
    }
    __syncthreads();
    {
        float a = 0.f;
        #pragma unroll
        for (int c = 0; c < 8; ++c) a += g1[p*8 + c]*Wo1[(p*8 + c)*64 + j];
        part[p][j] = a;
    }
    __syncthreads();
    if (t < 64) {
        float a = bo1[t];
        #pragma unroll
        for (int p2 = 0; p2 < 8; ++p2) a += part[p2][t];
        g2[t] = elu_(a);
    }
    __syncthreads();
    if (t < 10) { float a = bo2[t]; for (int c = 0; c < 64; ++c) a += g2[c]*Wo2[c*10 + t]; lg[t] = a; }
    __syncthreads();
    if (t == 0) {
        float mxl = lg[0];
        for (int i = 1; i < 10; ++i) mxl = fmaxf(mxl, lg[i]);
        float s = 0.f;
        for (int i = 0; i < 10; ++i) s += expf(lg[i] - mxl);
        const float lse = mxl + logf(s);
        for (int i = 0; i < 10; ++i) out[b*10 + i] = lg[i] - lse;
    }
}

extern "C" void kernel_launch(void* const* d_in, const int* in_sizes, int n_in,
                              void* d_out, int out_size, void* d_ws, size_t ws_size,
                              hipStream_t stream) {
    const float* x     = (const float*)d_in[0];
    const float* W_in0 = (const float*)d_in[1];
    const float* b_in0 = (const float*)d_in[2];
    const float* W_in1 = (const float*)d_in[3];
    const float* b_in1 = (const float*)d_in[4];
    const float* W_in2 = (const float*)d_in[5];
    const float* b_in2 = (const float*)d_in[6];
    const float* W_e0  = (const float*)d_in[7];   // [2,128,64]
    const float* b_e0  = (const float*)d_in[8];   // [2,64]
    const float* W_e1  = (const float*)d_in[9];   // [2,64,64]
    const float* b_e1  = (const float*)d_in[10];  // [2,64]
    const float* Wo0   = (const float*)d_in[11];
    const float* bo0   = (const float*)d_in[12];
    const float* Wo1   = (const float*)d_in[13];
    const float* bo1   = (const float*)d_in[14];
    const float* Wo2   = (const float*)d_in[15];
    const float* bo2   = (const float*)d_in[16];

    char* ws = (char*)d_ws;
    f16*    hA   = (f16*)(ws);                    // 8 MB
    f16*    hB   = (f16*)(ws + 8388608);          // 8 MB
    f16*    Pb   = (f16*)(ws + 16777216);         // 8 MB
    f16*    Qb   = (f16*)(ws + 25165824);         // 8 MB
    int*    idxb = (int*)(ws + 33554432);         // 4 MB
    float*  sqb  = (float*)(ws + 37748736);       // 256 KB

    // fused input MLP + sq  (P0/Q0 produced inside knn#1)
    mlp_kernel<<<1024, 256, 0, stream>>>(x, W_in0, b_in0, W_in1, b_in1, W_in2, b_in2,
                                         hA, sqb);
    // block 0 (knn fuses P0/Q0)
    knn_kernel<<<4096, 512, 0, stream>>>(hA, sqb, idxb, W_e0, b_e0, Pb, Qb);
    edge_kernel<<<2048, 256, 0, stream>>>(Pb, Qb, idxb, W_e1, b_e1, hB, sqb);
    // block 1 (knn fuses P1/Q1)
    knn_kernel<<<4096, 512, 0, stream>>>(hB, sqb, idxb, W_e0 + 8192, b_e0 + 64, Pb, Qb);
    edge_kernel<<<2048, 256, 0, stream>>>(Pb, Qb, idxb, W_e1 + 4096, b_e1 + 64, hA, sqb);

    final_kernel<<<128, 512, 0, stream>>>(hA, Wo0, bo0, Wo1, bo1, Wo2, bo2, (float*)d_out);
}

// Round 15
// 283.084 us; speedup vs baseline: 1.0050x; 1.0050x over previous
//
#include <hip/hip_runtime.h>
#include <hip/hip_fp16.h>
#include <cmath>

typedef _Float16 f16;
typedef _Float16 f16x8 __attribute__((ext_vector_type(8)));
typedef float f32x4 __attribute__((ext_vector_type(4)));

#define B_ 128
#define N_ 512
#define H_ 64
#define K_ 16

__device__ __forceinline__ float elu_(float x) { return x > 0.f ? x : (__expf(x) - 1.f); }
__device__ __forceinline__ unsigned umin_(unsigned a, unsigned b) { return a < b ? a : b; }
__device__ __forceinline__ unsigned umax_(unsigned a, unsigned b) { return a > b ? a : b; }
__device__ __forceinline__ f32x4 mfma16(f16x8 a, f16x8 b, f32x4 c) {
    return __builtin_amdgcn_mfma_f32_16x16x32_f16(a, b, c, 0, 0, 0);
}
__device__ __forceinline__ f32x4 splat4(float v) { f32x4 r; r[0]=v; r[1]=v; r[2]=v; r[3]=v; return r; }
__device__ __forceinline__ unsigned mbcnt_(unsigned long long mask) {
    return __builtin_amdgcn_mbcnt_hi((unsigned)(mask >> 32),
           __builtin_amdgcn_mbcnt_lo((unsigned)mask, 0u));
}
__device__ __forceinline__ f16 hexp_(f16 x) {
    __half h = *(__half*)&x; h = hexp(h); return *(f16*)&h;
}
// packed-f16 elu on 8 lanes: elu(x) = max(x,0) + exp(min(x,0)) - 1
__device__ __forceinline__ f16x8 elu8h_(f16x8 x) {
    f16x8 z; f16x8 one;
    #pragma unroll
    for (int i = 0; i < 8; ++i) { z[i] = (f16)0.f; one[i] = (f16)1.f; }
    f16x8 mx = __builtin_elementwise_max(x, z);
    f16x8 mn = __builtin_elementwise_min(x, z);
    f16x8 e;
    #pragma unroll
    for (int i = 0; i < 8; ++i) e[i] = hexp_(mn[i]);
    return mx + e - one;
}
// wave-wide max via DPP (VALU pipe, no ds_swizzle); canonical shr/bcast chain.
__device__ __forceinline__ unsigned wmax64_(unsigned v) {
    v = umax_(v, (unsigned)__builtin_amdgcn_update_dpp(0, (int)v, 0x111, 0xf, 0xf, true)); // row_shr:1
    v = umax_(v, (unsigned)__builtin_amdgcn_update_dpp(0, (int)v, 0x112, 0xf, 0xf, true)); // row_shr:2
    v = umax_(v, (unsigned)__builtin_amdgcn_update_dpp(0, (int)v, 0x114, 0xf, 0xf, true)); // row_shr:4
    v = umax_(v, (unsigned)__builtin_amdgcn_update_dpp(0, (int)v, 0x118, 0xf, 0xf, true)); // row_shr:8
    v = umax_(v, (unsigned)__builtin_amdgcn_update_dpp(0, (int)v, 0x142, 0xa, 0xf, true)); // row_bcast:15
    v = umax_(v, (unsigned)__builtin_amdgcn_update_dpp(0, (int)v, 0x143, 0xc, 0xf, true)); // row_bcast:31
    return (unsigned)__builtin_amdgcn_readlane((int)v, 63);
}
// add-reduce within each 16-lane row toward lane0 (valid in lane0 of each row)
__device__ __forceinline__ float rsum16lo_(float x) {
    x += __int_as_float(__builtin_amdgcn_update_dpp(0, __float_as_int(x), 0x101, 0xf, 0xf, true));
    x += __int_as_float(__builtin_amdgcn_update_dpp(0, __float_as_int(x), 0x102, 0xf, 0xf, true));
    x += __int_as_float(__builtin_amdgcn_update_dpp(0, __float_as_int(x), 0x104, 0xf, 0xf, true));
    x += __int_as_float(__builtin_amdgcn_update_dpp(0, __float_as_int(x), 0x108, 0xf, 0xf, true));
    return x;
}

// ---------------------------------------------------------------------------
// Fused input MLP (3 layers) + sq-norms. Per-wave LDS tile is private ->
// barrier-free. grid 1024 x block 256.
// ---------------------------------------------------------------------------
__global__ __launch_bounds__(256) void mlp_kernel(const float* __restrict__ x,
        const float* __restrict__ W0, const float* __restrict__ b0,
        const float* __restrict__ W1, const float* __restrict__ b1,
        const float* __restrict__ W2, const float* __restrict__ b2,
        f16* __restrict__ hout, float* __restrict__ sqout)
{
    __shared__ f16 tile[4][16*72];
    const int lane = threadIdx.x & 63, wid = threadIdx.x >> 6;
    const int m = lane & 15, q = lane >> 4;
    const int rowbase = blockIdx.x*64 + wid*16;
    f16* tw = tile[wid];

    // ---- layer 0: A = x (K=5 padded to 32) ----
    f16x8 af0, af1;
    {
        const float* xp = x + (size_t)(rowbase + m)*5;
        #pragma unroll
        for (int jj = 0; jj < 8; ++jj) { int k = q*8+jj; af0[jj] = (k < 5) ? (f16)xp[k] : (f16)0.f; }
    }
    f32x4 acc[4];
    #pragma unroll
    for (int t = 0; t < 4; ++t) {
        f16x8 bf;
        #pragma unroll
        for (int jj = 0; jj < 8; ++jj) { int k = q*8+jj; bf[jj] = (k < 5) ? (f16)W0[k*64 + t*16+m] : (f16)0.f; }
        acc[t] = splat4(b0[t*16+m]);
        acc[t] = mfma16(af0, bf, acc[t]);
    }
    #pragma unroll
    for (int t = 0; t < 4; ++t)
        #pragma unroll
        for (int r = 0; r < 4; ++r)
            tw[(q*4+r)*72 + t*16+m] = (f16)elu_(acc[t][r]);
    af0 = *(const f16x8*)(tw + m*72 + q*8);
    af1 = *(const f16x8*)(tw + m*72 + q*8 + 32);

    // ---- layer 1 ----
    #pragma unroll
    for (int t = 0; t < 4; ++t) {
        f16x8 bfa, bfb;
        #pragma unroll
        for (int jj = 0; jj < 8; ++jj) {
            bfa[jj] = (f16)W1[(q*8+jj)*64 + t*16+m];
            bfb[jj] = (f16)W1[(q*8+jj+32)*64 + t*16+m];
        }
        acc[t] = splat4(b1[t*16+m]);
        acc[t] = mfma16(af0, bfa, acc[t]);
        acc[t] = mfma16(af1, bfb, acc[t]);
    }
    #pragma unroll
    for (int t = 0; t < 4; ++t)
        #pragma unroll
        for (int r = 0; r < 4; ++r)
            tw[(q*4+r)*72 + t*16+m] = (f16)elu_(acc[t][r]);
    af0 = *(const f16x8*)(tw + m*72 + q*8);
    af1 = *(const f16x8*)(tw + m*72 + q*8 + 32);

    // ---- layer 2 (+ h store + sq) ----
    #pragma unroll
    for (int t = 0; t < 4; ++t) {
        f16x8 bfa, bfb;
        #pragma unroll
        for (int jj = 0; jj < 8; ++jj) {
            bfa[jj] = (f16)W2[(q*8+jj)*64 + t*16+m];
            bfb[jj] = (f16)W2[(q*8+jj+32)*64 + t*16+m];
        }
        acc[t] = splat4(b2[t*16+m]);
        acc[t] = mfma16(af0, bfa, acc[t]);
        acc[t] = mfma16(af1, bfb, acc[t]);
    }
    float s[4] = {0.f,0.f,0.f,0.f};
    #pragma unroll
    for (int t = 0; t < 4; ++t)
        #pragma unroll
        for (int r = 0; r < 4; ++r) {
            float v = elu_(acc[t][r]);
            hout[(size_t)(rowbase + q*4 + r)*64 + t*16 + m] = (f16)v;
            s[r] += v*v;
        }
    #pragma unroll
    for (int r = 0; r < 4; ++r) s[r] = rsum16lo_(s[r]);
    if (m == 0) {
        #pragma unroll
        for (int r = 0; r < 4; ++r) sqout[rowbase + q*4 + r] = s[r];
    }
}

// ---------------------------------------------------------------------------
// kNN (R9/R13 form, unchanged — 54.2 us measured): block 512, 4 blocks/CU at
// 32 KB LDS. Gram via MFMA; rank-17 ballot bit-descend threshold; batched-
// ballot compact; self-kill + DPP max-removal; fused next-layer P/Q
// projection after selection. grid 4096 x block 512.
// ---------------------------------------------------------------------------
__global__ __launch_bounds__(512, 8) void knn_kernel(const f16* __restrict__ hin,
        const float* __restrict__ sq, int* __restrict__ idxout,
        const float* __restrict__ We, const float* __restrict__ be,
        f16* __restrict__ Pout, f16* __restrict__ Qout)
{
    __shared__ unsigned keys[16*512];      // 32768 B exactly
    const int lane = threadIdx.x & 63;
    const int wid  = threadIdx.x >> 6;     // 0..7
    const int m = lane & 15, q = lane >> 4;
    const int b  = blockIdx.x >> 5;
    const int rt = blockIdx.x & 31;
    const int rowbase = rt*16;
    const f16* hb = hin + (size_t)b*N_*H_;
    const float* sqb = sq + b*N_;

    f16x8 af0, af1;
    {
        const f16* Ap = hb + (size_t)(rowbase + m)*64 + q*8;
        af0 = *(const f16x8*)Ap;
        af1 = *(const f16x8*)(Ap + 32);
    }
    const int colb0 = wid*16;
    f16x8 bf0[4], bf1[4];
    float sc[4];
    #pragma unroll
    for (int cti = 0; cti < 4; ++cti) {
        const f16* Bp = hb + (size_t)(colb0 + cti*128 + m)*64 + q*8;
        bf0[cti] = *(const f16x8*)Bp;
        bf1[cti] = *(const f16x8*)(Bp + 32);
        sc[cti] = sqb[colb0 + cti*128 + m];
    }
    int base_r[4];
    #pragma unroll
    for (int r = 0; r < 4; ++r) {
        const int row = q*4 + r;
        base_r[r] = row*512 + ((colb0 + m) ^ (row << 1));
    }
    #pragma unroll
    for (int cti = 0; cti < 4; ++cti) {
        f32x4 acc = splat4(0.f);
        acc = mfma16(af0, bf0[cti], acc);
        acc = mfma16(af1, bf1[cti], acc);
        #pragma unroll
        for (int r = 0; r < 4; ++r) {
            float d = fmaf(-2.f, acc[r], sc[cti]);   // sq_i dropped: row-constant
            unsigned u = __float_as_uint(d);
            u ^= (0x80000000u | (unsigned)((int)u >> 31));   // monotone order map
            unsigned key = (u & 0xFFFFFE00u) | (unsigned)(colb0 + cti*128 + m);
            keys[base_r[r] + cti*128] = key;         // immediate offset cti*512B
        }
    }
    __syncthreads();

    unsigned kk[2][8];
    #pragma unroll
    for (int rr = 0; rr < 2; ++rr) {
        const int ri = wid*2 + rr;
        *(uint4*)&kk[rr][0] = *(const uint4*)(keys + ri*512 + lane*4);
        *(uint4*)&kk[rr][4] = *(const uint4*)(keys + ri*512 + 256 + lane*4);
    }
    unsigned* scr = keys + wid*2*512;   // wave's own dead rows

    // ---- Phase A: per-lane min8, rank-17 ballot bit-descend threshold ----
    unsigned v[2];
    #pragma unroll
    for (int rr = 0; rr < 2; ++rr) {
        unsigned mn = kk[rr][0];
        #pragma unroll
        for (int s2 = 1; s2 < 8; ++s2) mn = umin_(mn, kk[rr][s2]);
        v[rr] = mn;
    }
    unsigned T[2] = {0u,0u};
    #pragma unroll
    for (int bit = 31; bit >= 9; --bit) {
        #pragma unroll
        for (int rr = 0; rr < 2; ++rr) {
            unsigned cand = T[rr] | (1u << bit);
            int c = __popcll(__ballot(v[rr] < cand));
            T[rr] = (c < 17) ? cand : T[rr];
        }
    }
    T[0] |= 511u; T[1] |= 511u;   // >=17 keys <= T (incl self)

    // ---- Phase B: batched-ballot compact ----
    unsigned cnt[2];
    #pragma unroll
    for (int rr = 0; rr < 2; ++rr) {
        unsigned long long bal[8];
        #pragma unroll
        for (int s2 = 0; s2 < 8; ++s2) bal[s2] = __ballot(kk[rr][s2] <= T[rr]);
        unsigned base = 0;
        #pragma unroll
        for (int s2 = 0; s2 < 8; ++s2) {
            if (kk[rr][s2] <= T[rr]) {
                unsigned pos = base + mbcnt_(bal[s2]);
                if (pos < 64u) scr[rr*64 + pos] = kk[rr][s2];
            }
            base += (unsigned)__popcll(bal[s2]);
        }
        cnt[rr] = base;
    }

    // ---- Phase C: kill self, DPP max-removal of (actives-16) largest ----
    #pragma unroll
    for (int rr = 0; rr < 2; ++rr) {
        const unsigned cc_ = umin_(cnt[rr], 64u);
        const int ri = wid*2 + rr;
        const unsigned rowglob = (unsigned)(rowbase + ri);
        bool act = lane < (int)cc_;
        unsigned mv = act ? scr[rr*64 + lane] : 0u;
        if (act && (mv & 511u) == rowglob) { act = false; mv = 0u; }  // self
        int e = __popcll(__ballot(act)) - 16;
        while (e > 0) {
            unsigned mx = wmax64_(mv);
            if (mv == mx) { act = false; mv = 0u; }
            --e;
        }
        int* outp = idxout + ((size_t)b*N_ + rowglob)*K_;
        unsigned long long bal = __ballot(act);       // exactly 16 lanes
        unsigned rank = mbcnt_(bal);
        if (act) outp[rank] = (int)(mv & 511u);
    }

    // ---- fused P/Q projection AFTER selection (hides in wave overlap) ----
    {
        const int t = wid & 3;
        f32x4 acc = (wid < 4) ? splat4(be[t*16+m]) : splat4(0.f);
        #pragma unroll
        for (int cc = 0; cc < 2; ++cc) {
            const f16x8 afc = cc ? af1 : af0;
            f16x8 bb;
            if (wid < 4) {
                #pragma unroll
                for (int jj = 0; jj < 8; ++jj) {
                    float wa = We[(q*8+jj+32*cc)*64 + t*16+m];
                    float wb = We[(q*8+jj+32*cc+64)*64 + t*16+m];
                    bb[jj] = (f16)(wa - wb);
                }
            } else {
                #pragma unroll
                for (int jj = 0; jj < 8; ++jj)
                    bb[jj] = (f16)We[(q*8+jj+32*cc+64)*64 + t*16+m];
            }
            acc = mfma16(afc, bb, acc);
        }
        f16* outp = (wid < 4) ? Pout : Qout;
        #pragma unroll
        for (int r = 0; r < 4; ++r)
            outp[((size_t)b*N_ + rowbase + q*4 + r)*64 + t*16 + m] = (f16)acc[r];
    }
}

// ---------------------------------------------------------------------------
// EdgeConv layer2 + sum aggregation + fused sq-norm. 4-node gather batching:
// 16 b128 loads in flight before compute (vs 8) to cover L2 latency;
// __launch_bounds__(256,4) gives ~128 VGPRs for the 64-VGPR buffer set
// (outstanding loads/CU: 20x8=160 -> 16x16=256). grid 2048 x 256.
// ---------------------------------------------------------------------------
__device__ __forceinline__ void edge_node_(size_t r0, f16x8 pa, f16x8 pb,
        f16x8 qa, f16x8 qb, const f16x8 (&bf)[2][4], const float (&bcol)[4],
        f16* __restrict__ out, float* __restrict__ sqout, int lane)
{
    f16x8 af0 = elu8h_(pa + qa);
    f16x8 af1 = elu8h_(pb + qb);
    f32x4 acc[4];
    #pragma unroll
    for (int t = 0; t < 4; ++t) acc[t] = splat4(bcol[t]);
    #pragma unroll
    for (int t = 0; t < 4; ++t) acc[t] = mfma16(af0, bf[0][t], acc[t]);
    #pragma unroll
    for (int t = 0; t < 4; ++t) acc[t] = mfma16(af1, bf[1][t], acc[t]);
    float ssum = 0.f;
    #pragma unroll
    for (int t = 0; t < 4; ++t) {
        float s = elu_(acc[t][0]) + elu_(acc[t][1]) + elu_(acc[t][2]) + elu_(acc[t][3]);
        s += __shfl_xor(s, 16);
        s += __shfl_xor(s, 32);
        if (lane < 16) out[r0*64 + t*16 + lane] = (f16)s;
        ssum += s*s;
    }
    ssum = rsum16lo_(ssum);
    if (lane == 0) sqout[r0] = ssum;
}

__global__ __launch_bounds__(256, 4) void edge_kernel(const f16* __restrict__ P,
        const f16* __restrict__ Q, const int* __restrict__ idx,
        const float* __restrict__ W1, const float* __restrict__ b1,
        f16* __restrict__ out, float* __restrict__ sqout)
{
    const int lane = threadIdx.x & 63;
    const int wid  = threadIdx.x >> 6;
    const int m = lane & 15, q = lane >> 4;

    f16x8 bf[2][4];
    #pragma unroll
    for (int cc = 0; cc < 2; ++cc)
        #pragma unroll
        for (int t = 0; t < 4; ++t)
            #pragma unroll
            for (int jj = 0; jj < 8; ++jj)
                bf[cc][t][jj] = (f16)W1[(q*8 + jj + 32*cc)*64 + t*16 + m];
    float bcol[4];
    #pragma unroll
    for (int t = 0; t < 4; ++t) bcol[t] = b1[t*16 + m];

    const int node0 = blockIdx.x*32 + wid*8;
    const int gbase = node0 & ~(N_-1);
    const int c0a = q*8, c0b = q*8 + 32;
    int jv[8];
    #pragma unroll
    for (int i = 0; i < 8; ++i) jv[i] = idx[(size_t)(node0 + i)*K_ + m];

    #pragma unroll
    for (int ib = 0; ib < 2; ++ib) {
        f16x8 pA[4], pB[4], qA[4], qB[4];
        #pragma unroll
        for (int k2 = 0; k2 < 4; ++k2) {
            const size_t r0 = (size_t)(node0 + ib*4 + k2);
            const size_t g0 = (size_t)(gbase + jv[ib*4 + k2]);
            pA[k2] = *(const f16x8*)(P + r0*64 + c0a);
            pB[k2] = *(const f16x8*)(P + r0*64 + c0b);
            qA[k2] = *(const f16x8*)(Q + g0*64 + c0a);
            qB[k2] = *(const f16x8*)(Q + g0*64 + c0b);
        }
        #pragma unroll
        for (int k2 = 0; k2 < 4; ++k2)
            edge_node_((size_t)(node0 + ib*4 + k2), pA[k2], pB[k2], qA[k2], qB[k2],
                       bf, bcol, out, sqout, lane);
    }
}

// ---------------------------------------------------------------------------
// Global max-pool + 3-layer output MLP + log_softmax. grid 128 x block 512.
// ---------------------------------------------------------------------------
__global__ __launch_bounds__(512) void final_kernel(const f16* __restrict__ hin,
        const float* __restrict__ Wo0, const float* __restrict__ bo0,
        const float* __restrict__ Wo1, const float* __restrict__ bo1,
        const float* __restrict__ Wo2, const float* __restrict__ bo2,
        float* __restrict__ out)
{
    __shared__ float smax[64][64];
    __shared__ float g0[64], g1[64], g2[64], part[8][64], lg[10];
    const int t = threadIdx.x;
    const int b = blockIdx.x;
    const int cg = t & 7, rg = t >> 3;

    float mx[8];
    #pragma unroll
    for (int e = 0; e < 8; ++e) mx[e] = -3.0e38f;
    #pragma unroll
    for (int i = 0; i < 8; ++i) {
        const int row = rg + i*64;
        f16x8 vv = *(const f16x8*)(hin + ((size_t)b*N_ + row)*64 + cg*8);
        #pragma unroll
        for (int e = 0; e < 8; ++e) mx[e] = fmaxf(mx[e], (float)vv[e]);
    }
    #pragma unroll
    for (int e = 0; e < 8; ++e) smax[rg][cg*8 + e] = mx[e];
    __syncthreads();
    for (int s = 32; s >= 1; s >>= 1) {
        if (rg < s) {
            #pragma unroll
            for (int e = 0; e < 8; ++e)
                smax[rg][cg*8+e] = fmaxf(smax[rg][cg*8+e], smax[rg+s][cg*8+e]);
        }
        __syncthreads();
    }
    if (t < 64) g0[t] = smax[0][t];
    __syncthreads();

    const int j = t & 63, p = t >> 6;
    {
        float a = 0.f;
        #pragma unroll
        for (int c = 0; c < 8; ++c) a += g0[p*8 + c]*Wo0[(p*8 + c)*64 + j];
        part[p][j] = a;
    }
    __syncthreads();
    if (t < 64) {
        float a = bo0[t];
        #pragma unroll
        for (int p2 = 0; p2 < 8; ++p2) a += part[p2][t];
        g1[t] = elu_(a);
    }
    __syncthreads();
    {
        float a = 0.f;
        #pragma unroll
        for (int c = 0; c < 8; ++c) a += g1[p*8 + c]*Wo1[(p*8 + c)*64 + j];
        part[p][j] = a;
    }
    __syncthreads();
    if (t < 64) {
        float a = bo1[t];
        #pragma unroll
        for (int p2 = 0; p2 < 8; ++p2) a += part[p2][t];
        g2[t] = elu_(a);
    }
    __syncthreads();
    if (t < 10) { float a = bo2[t]; for (int c = 0; c < 64; ++c) a += g2[c]*Wo2[c*10 + t]; lg[t] = a; }
    __syncthreads();
    if (t == 0) {
        float mxl = lg[0];
        for (int i = 1; i < 10; ++i) mxl = fmaxf(mxl, lg[i]);
        float s = 0.f;
        for (int i = 0; i < 10; ++i) s += expf(lg[i] - mxl);
        const float lse = mxl + logf(s);
        for (int i = 0; i < 10; ++i) out[b*10 + i] = lg[i] - lse;
    }
}

extern "C" void kernel_launch(void* const* d_in, const int* in_sizes, int n_in,
                              void* d_out, int out_size, void* d_ws, size_t ws_size,
                              hipStream_t stream) {
    const float* x     = (const float*)d_in[0];
    const float* W_in0 = (const float*)d_in[1];
    const float* b_in0 = (const float*)d_in[2];
    const float* W_in1 = (const float*)d_in[3];
    const float* b_in1 = (const float*)d_in[4];
    const float* W_in2 = (const float*)d_in[5];
    const float* b_in2 = (const float*)d_in[6];
    const float* W_e0  = (const float*)d_in[7];   // [2,128,64]
    const float* b_e0  = (const float*)d_in[8];   // [2,64]
    const float* W_e1  = (const float*)d_in[9];   // [2,64,64]
    const float* b_e1  = (const float*)d_in[10];  // [2,64]
    const float* Wo0   = (const float*)d_in[11];
    const float* bo0   = (const float*)d_in[12];
    const float* Wo1   = (const float*)d_in[13];
    const float* bo1   = (const float*)d_in[14];
    const float* Wo2   = (const float*)d_in[15];
    const float* bo2   = (const float*)d_in[16];

    char* ws = (char*)d_ws;
    f16*    hA   = (f16*)(ws);                    // 8 MB
    f16*    hB   = (f16*)(ws + 8388608);          // 8 MB
    f16*    Pb   = (f16*)(ws + 16777216);         // 8 MB
    f16*    Qb   = (f16*)(ws + 25165824);         // 8 MB
    int*    idxb = (int*)(ws + 33554432);         // 4 MB
    float*  sqb  = (float*)(ws + 37748736);       // 256 KB

    // fused input MLP + sq  (P0/Q0 produced inside knn#1)
    mlp_kernel<<<1024, 256, 0, stream>>>(x, W_in0, b_in0, W_in1, b_in1, W_in2, b_in2,
                                         hA, sqb);
    // block 0 (knn fuses P0/Q0)
    knn_kernel<<<4096, 512, 0, stream>>>(hA, sqb, idxb, W_e0, b_e0, Pb, Qb);
    edge_kernel<<<2048, 256, 0, stream>>>(Pb, Qb, idxb, W_e1, b_e1, hB, sqb);
    // block 1 (knn fuses P1/Q1)
    knn_kernel<<<4096, 512, 0, stream>>>(hB, sqb, idxb, W_e0 + 8192, b_e0 + 64, Pb, Qb);
    edge_kernel<<<2048, 256, 0, stream>>>(Pb, Qb, idxb, W_e1 + 4096, b_e1 + 64, hA, sqb);

    final_kernel<<<128, 512, 0, stream>>>(hA, Wo0, bo0, Wo1, bo1, Wo2, bo2, (float*)d_out);
}

// Round 16
// 280.457 us; speedup vs baseline: 1.0145x; 1.0094x over previous
//
#include <hip/hip_runtime.h>
#include <hip/hip_fp16.h>
#include <cmath>

typedef _Float16 f16;
typedef _Float16 f16x8 __attribute__((ext_vector_type(8)));
typedef float f32x4 __attribute__((ext_vector_type(4)));

#define B_ 128
#define N_ 512
#define H_ 64
#define K_ 16

__device__ __forceinline__ float elu_(float x) { return x > 0.f ? x : (__expf(x) - 1.f); }
__device__ __forceinline__ unsigned umin_(unsigned a, unsigned b) { return a < b ? a : b; }
__device__ __forceinline__ unsigned umax_(unsigned a, unsigned b) { return a > b ? a : b; }
__device__ __forceinline__ f32x4 mfma16(f16x8 a, f16x8 b, f32x4 c) {
    return __builtin_amdgcn_mfma_f32_16x16x32_f16(a, b, c, 0, 0, 0);
}
__device__ __forceinline__ f32x4 splat4(float v) { f32x4 r; r[0]=v; r[1]=v; r[2]=v; r[3]=v; return r; }
__device__ __forceinline__ unsigned mbcnt_(unsigned long long mask) {
    return __builtin_amdgcn_mbcnt_hi((unsigned)(mask >> 32),
           __builtin_amdgcn_mbcnt_lo((unsigned)mask, 0u));
}
__device__ __forceinline__ f16 hexp_(f16 x) {
    __half h = *(__half*)&x; h = hexp(h); return *(f16*)&h;
}
// packed-f16 elu on 8 lanes: elu(x) = max(x,0) + exp(min(x,0)) - 1
__device__ __forceinline__ f16x8 elu8h_(f16x8 x) {
    f16x8 z; f16x8 one;
    #pragma unroll
    for (int i = 0; i < 8; ++i) { z[i] = (f16)0.f; one[i] = (f16)1.f; }
    f16x8 mx = __builtin_elementwise_max(x, z);
    f16x8 mn = __builtin_elementwise_min(x, z);
    f16x8 e;
    #pragma unroll
    for (int i = 0; i < 8; ++i) e[i] = hexp_(mn[i]);
    return mx + e - one;
}
// wave-wide max via DPP (VALU pipe, no ds_swizzle); canonical shr/bcast chain.
__device__ __forceinline__ unsigned wmax64_(unsigned v) {
    v = umax_(v, (unsigned)__builtin_amdgcn_update_dpp(0, (int)v, 0x111, 0xf, 0xf, true)); // row_shr:1
    v = umax_(v, (unsigned)__builtin_amdgcn_update_dpp(0, (int)v, 0x112, 0xf, 0xf, true)); // row_shr:2
    v = umax_(v, (unsigned)__builtin_amdgcn_update_dpp(0, (int)v, 0x114, 0xf, 0xf, true)); // row_shr:4
    v = umax_(v, (unsigned)__builtin_amdgcn_update_dpp(0, (int)v, 0x118, 0xf, 0xf, true)); // row_shr:8
    v = umax_(v, (unsigned)__builtin_amdgcn_update_dpp(0, (int)v, 0x142, 0xa, 0xf, true)); // row_bcast:15
    v = umax_(v, (unsigned)__builtin_amdgcn_update_dpp(0, (int)v, 0x143, 0xc, 0xf, true)); // row_bcast:31
    return (unsigned)__builtin_amdgcn_readlane((int)v, 63);
}
// add-reduce within each 16-lane row toward lane0 (valid in lane0 of each row)
__device__ __forceinline__ float rsum16lo_(float x) {
    x += __int_as_float(__builtin_amdgcn_update_dpp(0, __float_as_int(x), 0x101, 0xf, 0xf, true));
    x += __int_as_float(__builtin_amdgcn_update_dpp(0, __float_as_int(x), 0x102, 0xf, 0xf, true));
    x += __int_as_float(__builtin_amdgcn_update_dpp(0, __float_as_int(x), 0x104, 0xf, 0xf, true));
    x += __int_as_float(__builtin_amdgcn_update_dpp(0, __float_as_int(x), 0x108, 0xf, 0xf, true));
    return x;
}

// ---------------------------------------------------------------------------
// Fused input MLP (3 layers) + sq-norms. NEW: W1/W2 staged once per block
// into LDS (transposed WT[n][k], f16, row stride 80 f16 -> 16B-aligned b128
// fragment reads, <=4-way bank aliasing) — replaces 64 global loads + 64
// cvt per layer per wave with 8 ds_read_b128. Value-exact (same f16
// rounding). Per-wave tile stays private -> only the one staging barrier.
// grid 1024 x block 256.
// ---------------------------------------------------------------------------
__global__ __launch_bounds__(256) void mlp_kernel(const float* __restrict__ x,
        const float* __restrict__ W0, const float* __restrict__ b0,
        const float* __restrict__ W1, const float* __restrict__ b1,
        const float* __restrict__ W2, const float* __restrict__ b2,
        f16* __restrict__ hout, float* __restrict__ sqout)
{
    __shared__ f16 tile[4][16*72];
    __shared__ f16 w1t[64*80];
    __shared__ f16 w2t[64*80];
    const int tid = threadIdx.x;
    const int lane = tid & 63, wid = tid >> 6;
    const int m = lane & 15, q = lane >> 4;
    const int rowbase = blockIdx.x*64 + wid*16;
    f16* tw = tile[wid];

    // ---- stage W1/W2 -> LDS (transposed, f16) ----
    {
        const int k  = tid >> 2;
        const int n0 = (tid & 3) << 4;
        #pragma unroll
        for (int jj = 0; jj < 4; ++jj) {
            const float4 v1 = *(const float4*)(W1 + k*64 + n0 + jj*4);
            const float4 v2 = *(const float4*)(W2 + k*64 + n0 + jj*4);
            const int nb = n0 + jj*4;
            w1t[(nb+0)*80 + k] = (f16)v1.x; w1t[(nb+1)*80 + k] = (f16)v1.y;
            w1t[(nb+2)*80 + k] = (f16)v1.z; w1t[(nb+3)*80 + k] = (f16)v1.w;
            w2t[(nb+0)*80 + k] = (f16)v2.x; w2t[(nb+1)*80 + k] = (f16)v2.y;
            w2t[(nb+2)*80 + k] = (f16)v2.z; w2t[(nb+3)*80 + k] = (f16)v2.w;
        }
    }

    // ---- layer 0: A = x (K=5 padded to 32), W0 via global (tiny) ----
    f16x8 af0, af1;
    {
        const float* xp = x + (size_t)(rowbase + m)*5;
        #pragma unroll
        for (int jj = 0; jj < 8; ++jj) { int k = q*8+jj; af0[jj] = (k < 5) ? (f16)xp[k] : (f16)0.f; }
    }
    f32x4 acc[4];
    #pragma unroll
    for (int t = 0; t < 4; ++t) {
        f16x8 bf;
        #pragma unroll
        for (int jj = 0; jj < 8; ++jj) { int k = q*8+jj; bf[jj] = (k < 5) ? (f16)W0[k*64 + t*16+m] : (f16)0.f; }
        acc[t] = splat4(b0[t*16+m]);
        acc[t] = mfma16(af0, bf, acc[t]);
    }
    #pragma unroll
    for (int t = 0; t < 4; ++t)
        #pragma unroll
        for (int r = 0; r < 4; ++r)
            tw[(q*4+r)*72 + t*16+m] = (f16)elu_(acc[t][r]);
    af0 = *(const f16x8*)(tw + m*72 + q*8);
    af1 = *(const f16x8*)(tw + m*72 + q*8 + 32);
    __syncthreads();   // w1t/w2t ready

    // ---- layer 1 (fragments from LDS) ----
    #pragma unroll
    for (int t = 0; t < 4; ++t) {
        f16x8 bfa = *(const f16x8*)(w1t + (t*16+m)*80 + q*8);
        f16x8 bfb = *(const f16x8*)(w1t + (t*16+m)*80 + q*8 + 32);
        acc[t] = splat4(b1[t*16+m]);
        acc[t] = mfma16(af0, bfa, acc[t]);
        acc[t] = mfma16(af1, bfb, acc[t]);
    }
    #pragma unroll
    for (int t = 0; t < 4; ++t)
        #pragma unroll
        for (int r = 0; r < 4; ++r)
            tw[(q*4+r)*72 + t*16+m] = (f16)elu_(acc[t][r]);
    af0 = *(const f16x8*)(tw + m*72 + q*8);
    af1 = *(const f16x8*)(tw + m*72 + q*8 + 32);

    // ---- layer 2 (fragments from LDS; + h store + sq) ----
    #pragma unroll
    for (int t = 0; t < 4; ++t) {
        f16x8 bfa = *(const f16x8*)(w2t + (t*16+m)*80 + q*8);
        f16x8 bfb = *(const f16x8*)(w2t + (t*16+m)*80 + q*8 + 32);
        acc[t] = splat4(b2[t*16+m]);
        acc[t] = mfma16(af0, bfa, acc[t]);
        acc[t] = mfma16(af1, bfb, acc[t]);
    }
    float s[4] = {0.f,0.f,0.f,0.f};
    #pragma unroll
    for (int t = 0; t < 4; ++t)
        #pragma unroll
        for (int r = 0; r < 4; ++r) {
            float v = elu_(acc[t][r]);
            hout[(size_t)(rowbase + q*4 + r)*64 + t*16 + m] = (f16)v;
            s[r] += v*v;
        }
    #pragma unroll
    for (int r = 0; r < 4; ++r) s[r] = rsum16lo_(s[r]);
    if (m == 0) {
        #pragma unroll
        for (int r = 0; r < 4; ++r) sqout[rowbase + q*4 + r] = s[r];
    }
}

// ---------------------------------------------------------------------------
// kNN (R9/R13 form, unchanged — 54.3 us measured): block 512, 4 blocks/CU at
// 32 KB LDS. Gram via MFMA; rank-17 ballot bit-descend threshold; batched-
// ballot compact; self-kill + DPP max-removal; fused next-layer P/Q
// projection after selection. grid 4096 x block 512.
// ---------------------------------------------------------------------------
__global__ __launch_bounds__(512, 8) void knn_kernel(const f16* __restrict__ hin,
        const float* __restrict__ sq, int* __restrict__ idxout,
        const float* __restrict__ We, const float* __restrict__ be,
        f16* __restrict__ Pout, f16* __restrict__ Qout)
{
    __shared__ unsigned keys[16*512];      // 32768 B exactly
    const int lane = threadIdx.x & 63;
    const int wid  = threadIdx.x >> 6;     // 0..7
    const int m = lane & 15, q = lane >> 4;
    const int b  = blockIdx.x >> 5;
    const int rt = blockIdx.x & 31;
    const int rowbase = rt*16;
    const f16* hb = hin + (size_t)b*N_*H_;
    const float* sqb = sq + b*N_;

    f16x8 af0, af1;
    {
        const f16* Ap = hb + (size_t)(rowbase + m)*64 + q*8;
        af0 = *(const f16x8*)Ap;
        af1 = *(const f16x8*)(Ap + 32);
    }
    const int colb0 = wid*16;
    f16x8 bf0[4], bf1[4];
    float sc[4];
    #pragma unroll
    for (int cti = 0; cti < 4; ++cti) {
        const f16* Bp = hb + (size_t)(colb0 + cti*128 + m)*64 + q*8;
        bf0[cti] = *(const f16x8*)Bp;
        bf1[cti] = *(const f16x8*)(Bp + 32);
        sc[cti] = sqb[colb0 + cti*128 + m];
    }
    int base_r[4];
    #pragma unroll
    for (int r = 0; r < 4; ++r) {
        const int row = q*4 + r;
        base_r[r] = row*512 + ((colb0 + m) ^ (row << 1));
    }
    #pragma unroll
    for (int cti = 0; cti < 4; ++cti) {
        f32x4 acc = splat4(0.f);
        acc = mfma16(af0, bf0[cti], acc);
        acc = mfma16(af1, bf1[cti], acc);
        #pragma unroll
        for (int r = 0; r < 4; ++r) {
            float d = fmaf(-2.f, acc[r], sc[cti]);   // sq_i dropped: row-constant
            unsigned u = __float_as_uint(d);
            u ^= (0x80000000u | (unsigned)((int)u >> 31));   // monotone order map
            unsigned key = (u & 0xFFFFFE00u) | (unsigned)(colb0 + cti*128 + m);
            keys[base_r[r] + cti*128] = key;         // immediate offset cti*512B
        }
    }
    __syncthreads();

    unsigned kk[2][8];
    #pragma unroll
    for (int rr = 0; rr < 2; ++rr) {
        const int ri = wid*2 + rr;
        *(uint4*)&kk[rr][0] = *(const uint4*)(keys + ri*512 + lane*4);
        *(uint4*)&kk[rr][4] = *(const uint4*)(keys + ri*512 + 256 + lane*4);
    }
    unsigned* scr = keys + wid*2*512;   // wave's own dead rows

    // ---- Phase A: per-lane min8, rank-17 ballot bit-descend threshold ----
    unsigned v[2];
    #pragma unroll
    for (int rr = 0; rr < 2; ++rr) {
        unsigned mn = kk[rr][0];
        #pragma unroll
        for (int s2 = 1; s2 < 8; ++s2) mn = umin_(mn, kk[rr][s2]);
        v[rr] = mn;
    }
    unsigned T[2] = {0u,0u};
    #pragma unroll
    for (int bit = 31; bit >= 9; --bit) {
        #pragma unroll
        for (int rr = 0; rr < 2; ++rr) {
            unsigned cand = T[rr] | (1u << bit);
            int c = __popcll(__ballot(v[rr] < cand));
            T[rr] = (c < 17) ? cand : T[rr];
        }
    }
    T[0] |= 511u; T[1] |= 511u;   // >=17 keys <= T (incl self)

    // ---- Phase B: batched-ballot compact ----
    unsigned cnt[2];
    #pragma unroll
    for (int rr = 0; rr < 2; ++rr) {
        unsigned long long bal[8];
        #pragma unroll
        for (int s2 = 0; s2 < 8; ++s2) bal[s2] = __ballot(kk[rr][s2] <= T[rr]);
        unsigned base = 0;
        #pragma unroll
        for (int s2 = 0; s2 < 8; ++s2) {
            if (kk[rr][s2] <= T[rr]) {
                unsigned pos = base + mbcnt_(bal[s2]);
                if (pos < 64u) scr[rr*64 + pos] = kk[rr][s2];
            }
            base += (unsigned)__popcll(bal[s2]);
        }
        cnt[rr] = base;
    }

    // ---- Phase C: kill self, DPP max-removal of (actives-16) largest ----
    #pragma unroll
    for (int rr = 0; rr < 2; ++rr) {
        const unsigned cc_ = umin_(cnt[rr], 64u);
        const int ri = wid*2 + rr;
        const unsigned rowglob = (unsigned)(rowbase + ri);
        bool act = lane < (int)cc_;
        unsigned mv = act ? scr[rr*64 + lane] : 0u;
        if (act && (mv & 511u) == rowglob) { act = false; mv = 0u; }  // self
        int e = __popcll(__ballot(act)) - 16;
        while (e > 0) {
            unsigned mx = wmax64_(mv);
            if (mv == mx) { act = false; mv = 0u; }
            --e;
        }
        int* outp = idxout + ((size_t)b*N_ + rowglob)*K_;
        unsigned long long bal = __ballot(act);       // exactly 16 lanes
        unsigned rank = mbcnt_(bal);
        if (act) outp[rank] = (int)(mv & 511u);
    }

    // ---- fused P/Q projection AFTER selection (hides in wave overlap) ----
    {
        const int t = wid & 3;
        f32x4 acc = (wid < 4) ? splat4(be[t*16+m]) : splat4(0.f);
        #pragma unroll
        for (int cc = 0; cc < 2; ++cc) {
            const f16x8 afc = cc ? af1 : af0;
            f16x8 bb;
            if (wid < 4) {
                #pragma unroll
                for (int jj = 0; jj < 8; ++jj) {
                    float wa = We[(q*8+jj+32*cc)*64 + t*16+m];
                    float wb = We[(q*8+jj+32*cc+64)*64 + t*16+m];
                    bb[jj] = (f16)(wa - wb);
                }
            } else {
                #pragma unroll
                for (int jj = 0; jj < 8; ++jj)
                    bb[jj] = (f16)We[(q*8+jj+32*cc+64)*64 + t*16+m];
            }
            acc = mfma16(afc, bb, acc);
        }
        f16* outp = (wid < 4) ? Pout : Qout;
        #pragma unroll
        for (int r = 0; r < 4; ++r)
            outp[((size_t)b*N_ + rowbase + q*4 + r)*64 + t*16 + m] = (f16)acc[r];
    }
}

// ---------------------------------------------------------------------------
// EdgeConv layer2 + sum aggregation + fused sq-norm. 4-node gather batching;
// grid 4096 (16 nodes/block, 4/wave): halves per-wave prologue and smooths
// the drain tail (4 residency rounds vs 2). grid 4096 x 256.
// ---------------------------------------------------------------------------
__device__ __forceinline__ void edge_node_(size_t r0, f16x8 pa, f16x8 pb,
        f16x8 qa, f16x8 qb, const f16x8 (&bf)[2][4], const float (&bcol)[4],
        f16* __restrict__ out, float* __restrict__ sqout, int lane)
{
    f16x8 af0 = elu8h_(pa + qa);
    f16x8 af1 = elu8h_(pb + qb);
    f32x4 acc[4];
    #pragma unroll
    for (int t = 0; t < 4; ++t) acc[t] = splat4(bcol[t]);
    #pragma unroll
    for (int t = 0; t < 4; ++t) acc[t] = mfma16(af0, bf[0][t], acc[t]);
    #pragma unroll
    for (int t = 0; t < 4; ++t) acc[t] = mfma16(af1, bf[1][t], acc[t]);
    float ssum = 0.f;
    #pragma unroll
    for (int t = 0; t < 4; ++t) {
        float s = elu_(acc[t][0]) + elu_(acc[t][1]) + elu_(acc[t][2]) + elu_(acc[t][3]);
        s += __shfl_xor(s, 16);
        s += __shfl_xor(s, 32);
        if (lane < 16) out[r0*64 + t*16 + lane] = (f16)s;
        ssum += s*s;
    }
    ssum = rsum16lo_(ssum);
    if (lane == 0) sqout[r0] = ssum;
}

__global__ __launch_bounds__(256, 4) void edge_kernel(const f16* __restrict__ P,
        const f16* __restrict__ Q, const int* __restrict__ idx,
        const float* __restrict__ W1, const float* __restrict__ b1,
        f16* __restrict__ out, float* __restrict__ sqout)
{
    const int lane = threadIdx.x & 63;
    const int wid  = threadIdx.x >> 6;
    const int m = lane & 15, q = lane >> 4;

    f16x8 bf[2][4];
    #pragma unroll
    for (int cc = 0; cc < 2; ++cc)
        #pragma unroll
        for (int t = 0; t < 4; ++t)
            #pragma unroll
            for (int jj = 0; jj < 8; ++jj)
                bf[cc][t][jj] = (f16)W1[(q*8 + jj + 32*cc)*64 + t*16 + m];
    float bcol[4];
    #pragma unroll
    for (int t = 0; t < 4; ++t) bcol[t] = b1[t*16 + m];

    const int node0 = blockIdx.x*16 + wid*4;
    const int gbase = node0 & ~(N_-1);
    const int c0a = q*8, c0b = q*8 + 32;
    int jv[4];
    #pragma unroll
    for (int i = 0; i < 4; ++i) jv[i] = idx[(size_t)(node0 + i)*K_ + m];

    f16x8 pA[4], pB[4], qA[4], qB[4];
    #pragma unroll
    for (int k2 = 0; k2 < 4; ++k2) {
        const size_t r0 = (size_t)(node0 + k2);
        const size_t g0 = (size_t)(gbase + jv[k2]);
        pA[k2] = *(const f16x8*)(P + r0*64 + c0a);
        pB[k2] = *(const f16x8*)(P + r0*64 + c0b);
        qA[k2] = *(const f16x8*)(Q + g0*64 + c0a);
        qB[k2] = *(const f16x8*)(Q + g0*64 + c0b);
    }
    #pragma unroll
    for (int k2 = 0; k2 < 4; ++k2)
        edge_node_((size_t)(node0 + k2), pA[k2], pB[k2], qA[k2], qB[k2],
                   bf, bcol, out, sqout, lane);
}

// ---------------------------------------------------------------------------
// Global max-pool + 3-layer output MLP + log_softmax. grid 128 x block 512.
// ---------------------------------------------------------------------------
__global__ __launch_bounds__(512) void final_kernel(const f16* __restrict__ hin,
        const float* __restrict__ Wo0, const float* __restrict__ bo0,
        const float* __restrict__ Wo1, const float* __restrict__ bo1,
        const float* __restrict__ Wo2, const float* __restrict__ bo2,
        float* __restrict__ out)
{
    __shared__ float smax[64][64];
    __shared__ float g0[64], g1[64], g2[64], part[8][64], lg[10];
    const int t = threadIdx.x;
    const int b = blockIdx.x;
    const int cg = t & 7, rg = t >> 3;

    float mx[8];
    #pragma unroll
    for (int e = 0; e < 8; ++e) mx[e] = -3.0e38f;
    #pragma unroll
    for (int i = 0; i < 8; ++i) {
        const int row = rg + i*64;
        f16x8 vv = *(const f16x8*)(hin + ((size_t)b*N_ + row)*64 + cg*8);
        #pragma unroll
        for (int e = 0; e < 8; ++e) mx[e] = fmaxf(mx[e], (float)vv[e]);
    }
    #pragma unroll
    for (int e = 0; e < 8; ++e) smax[rg][cg*8 + e] = mx[e];
    __syncthreads();
    for (int s = 32; s >= 1; s >>= 1) {
        if (rg < s) {
            #pragma unroll
            for (int e = 0; e < 8; ++e)
                smax[rg][cg*8+e] = fmaxf(smax[rg][cg*8+e], smax[rg+s][cg*8+e]);
        }
        __syncthreads();
    }
    if (t < 64) g0[t] = smax[0][t];
    __syncthreads();

    const int j = t & 63, p = t >> 6;
    {
        float a = 0.f;
        #pragma unroll
        for (int c = 0; c < 8; ++c) a += g0[p*8 + c]*Wo0[(p*8 + c)*64 + j];
        part[p][j] = a;
    }
    __syncthreads();
    if (t < 64) {
        float a = bo0[t];
        #pragma unroll
        for (int p2 = 0; p2 < 8; ++p2) a += part[p2][t];
        g1[t] = elu_(a);
    }
    __syncthreads();
    {
        float a = 0.f;
        #pragma unroll
        for (int c = 0; c < 8; ++c) a += g1[p*8 + c]*Wo1[(p*8 + c)*64 + j];
        part[p][j] = a;
    }
    __syncthreads();
    if (t < 64) {
        float a = bo1[t];
        #pragma unroll
        for (int p2 = 0; p2 < 8; ++p2) a += part[p2][t];
        g2[t] = elu_(a);
    }
    __syncthreads();
    if (t < 10) { float a = bo2[t]; for (int c = 0; c < 64; ++c) a += g2[c]*Wo2[c*10 + t]; lg[t] = a; }
    __syncthreads();
    if (t == 0) {
        float mxl = lg[0];
        for (int i = 1; i < 10; ++i) mxl = fmaxf(mxl, lg[i]);
        float s = 0.f;
        for (int i = 0; i < 10; ++i) s += expf(lg[i] - mxl);
        const float lse = mxl + logf(s);
        for (int i = 0; i < 10; ++i) out[b*10 + i] = lg[i] - lse;
    }
}

extern "C" void kernel_launch(void* const* d_in, const int* in_sizes, int n_in,
                              void* d_out, int out_size, void* d_ws, size_t ws_size,
                              hipStream_t stream) {
    const float* x     = (const float*)d_in[0];
    const float* W_in0 = (const float*)d_in[1];
    const float* b_in0 = (const float*)d_in[2];
    const float* W_in1 = (const float*)d_in[3];
    const float* b_in1 = (const float*)d_in[4];
    const float* W_in2 = (const float*)d_in[5];
    const float* b_in2 = (const float*)d_in[6];
    const float* W_e0  = (const float*)d_in[7];   // [2,128,64]
    const float* b_e0  = (const float*)d_in[8];   // [2,64]
    const float* W_e1  = (const float*)d_in[9];   // [2,64,64]
    const float* b_e1  = (const float*)d_in[10];  // [2,64]
    const float* Wo0   = (const float*)d_in[11];
    const float* bo0   = (const float*)d_in[12];
    const float* Wo1   = (const float*)d_in[13];
    const float* bo1   = (const float*)d_in[14];
    const float* Wo2   = (const float*)d_in[15];
    const float* bo2   = (const float*)d_in[16];

    char* ws = (char*)d_ws;
    f16*    hA   = (f16*)(ws);                    // 8 MB
    f16*    hB   = (f16*)(ws + 8388608);          // 8 MB
    f16*    Pb   = (f16*)(ws + 16777216);         // 8 MB
    f16*    Qb   = (f16*)(ws + 25165824);         // 8 MB
    int*    idxb = (int*)(ws + 33554432);         // 4 MB
    float*  sqb  = (float*)(ws + 37748736);       // 256 KB

    // fused input MLP + sq  (P0/Q0 produced inside knn#1)
    mlp_kernel<<<1024, 256, 0, stream>>>(x, W_in0, b_in0, W_in1, b_in1, W_in2, b_in2,
                                         hA, sqb);
    // block 0 (knn fuses P0/Q0)
    knn_kernel<<<4096, 512, 0, stream>>>(hA, sqb, idxb, W_e0, b_e0, Pb, Qb);
    edge_kernel<<<4096, 256, 0, stream>>>(Pb, Qb, idxb, W_e1, b_e1, hB, sqb);
    // block 1 (knn fuses P1/Q1)
    knn_kernel<<<4096, 512, 0, stream>>>(hB, sqb, idxb, W_e0 + 8192, b_e0 + 64, Pb, Qb);
    edge_kernel<<<4096, 256, 0, stream>>>(Pb, Qb, idxb, W_e1 + 4096, b_e1 + 64, hA, sqb);

    final_kernel<<<128, 512, 0, stream>>>(hA, Wo0, bo0, Wo1, bo1, Wo2, bo2, (float*)d_out);
}